// Round 22
// baseline (101.184 us; speedup 1.0000x reference)
//
#include <hip/hip_runtime.h>

#define T 256
#define CH 4096          // bin width (12-bit localdst), 16 KB LDS
#define SHIFT 12
#define BB 1024          // binning blocks (4/CU)
#define NWV 4            // waves per block
#define NSH 8            // shadow regions per partition (blockIdx & 7)
#define NSL2 4           // slices per virtual bin (r20 best)
#define NSL 32           // = NSH*NSL2, slices per partition
#define PMAX 32

// ---------- fused count+reserve+place: closed-form shadow regions (r17) ----------
__global__ void k_binfused(const int* __restrict__ src, const int* __restrict__ dst,
                           int e, int P, int capg, int* __restrict__ cursor2,
                           unsigned* __restrict__ binned) {
    const int b = blockIdx.x;
    const int t = threadIdx.x;
    const int lane = t & 63, w = t >> 6;
    __shared__ int wcnt[NWV][PMAX];
    __shared__ int lbase[NWV][PMAX];
    __shared__ int lcur[NWV][PMAX];

    // ---- loop 1: per-thread register counts ----
    int cnt[PMAX];
#pragma unroll
    for (int k = 0; k < PMAX; ++k) cnt[k] = 0;
    const int nv4 = e >> 2;
    const int s4 = (int)((long)b * nv4 / BB);
    const int e4 = (int)((long)(b + 1) * nv4 / BB);
    const int4* d4 = (const int4*)dst;
    const int4* s4p = (const int4*)src;
    for (int i = s4 + t; i < e4; i += T) {
        int4 d = d4[i];
        int px = d.x >> SHIFT, py = d.y >> SHIFT, pz = d.z >> SHIFT, pw = d.w >> SHIFT;
#pragma unroll
        for (int k = 0; k < PMAX; ++k)
            cnt[k] += (px == k) + (py == k) + (pz == k) + (pw == k);
    }
    if (b == BB - 1) {
        for (int j = (nv4 << 2) + t; j < e; j += T) {
            int p = dst[j] >> SHIFT;
#pragma unroll
            for (int k = 0; k < PMAX; ++k) cnt[k] += (p == k);
        }
    }
    // ---- per-wave reduce into LDS ----
#pragma unroll
    for (int k = 0; k < PMAX; ++k) {
        int v = cnt[k];
        for (int off = 32; off; off >>= 1) v += __shfl_down(v, off);
        if (lane == 0) wcnt[w][k] = v;
    }
    __syncthreads();
    // ---- reserve: one atomic per (block, partition) on the block's shadow cursor ----
    if (t < P) {
        int c0 = wcnt[0][t], c1 = wcnt[1][t], c2 = wcnt[2][t], c3 = wcnt[3][t];
        int tot = c0 + c1 + c2 + c3;
        int g = b & (NSH - 1);
        int off = tot ? atomicAdd(&cursor2[g * 32 + t], tot) : 0;
        int base = (t * NSH + g) * capg + off;      // closed-form region start, no division
        lbase[0][t] = base;                lcur[0][t] = 0;
        lbase[1][t] = base + c0;           lcur[1][t] = 0;
        lbase[2][t] = base + c0 + c1;      lcur[2][t] = 0;
        lbase[3][t] = base + c0 + c1 + c2; lcur[3][t] = 0;
    }
    __syncthreads();

    // ---- loop 2: place via per-wave LDS cursors ----
    for (int i = s4 + t; i < e4; i += T) {
        int4 d = d4[i];
        int4 s = s4p[i];
        int pb, off;
        pb = d.x >> SHIFT; off = atomicAdd(&lcur[w][pb], 1);
        binned[lbase[w][pb] + off] = ((unsigned)s.x << SHIFT) | (unsigned)(d.x & (CH - 1));
        pb = d.y >> SHIFT; off = atomicAdd(&lcur[w][pb], 1);
        binned[lbase[w][pb] + off] = ((unsigned)s.y << SHIFT) | (unsigned)(d.y & (CH - 1));
        pb = d.z >> SHIFT; off = atomicAdd(&lcur[w][pb], 1);
        binned[lbase[w][pb] + off] = ((unsigned)s.z << SHIFT) | (unsigned)(d.z & (CH - 1));
        pb = d.w >> SHIFT; off = atomicAdd(&lcur[w][pb], 1);
        binned[lbase[w][pb] + off] = ((unsigned)s.w << SHIFT) | (unsigned)(d.w & (CH - 1));
    }
    if (b == BB - 1) {
        for (int j = (nv4 << 2) + t; j < e; j += T) {
            int d = dst[j];
            int pb = d >> SHIFT;
            int off = atomicAdd(&lcur[w][pb], 1);
            binned[lbase[w][pb] + off] = ((unsigned)src[j] << SHIFT) | (unsigned)(d & (CH - 1));
        }
    }
}

// ---------- degree histogram per (vbin, slice), 8-deep ILP, ushort output ----------
__global__ void k_histA(const unsigned* __restrict__ binned, const int* __restrict__ cursor2,
                        int capg, unsigned short* __restrict__ sliceCnt) {
    const int s = blockIdx.x % NSL2;
    const int vb = blockIdx.x / NSL2;          // vb = p*NSH + g
    const int p = vb / NSH, g = vb % NSH;
    __shared__ int cnt[CH];
    for (int t = threadIdx.x; t < CH; t += T) cnt[t] = 0;
    __syncthreads();
    const int s0 = vb * capg;
    const int len = cursor2[g * 32 + p];
    const int a = s0 + (int)((long)s * len / NSL2);
    const int b = s0 + (int)((long)(s + 1) * len / NSL2);
    int i = a + threadIdx.x;
    for (; i + 7 * T < b; i += 8 * T) {
        unsigned r0 = binned[i];
        unsigned r1 = binned[i + T];
        unsigned r2 = binned[i + 2 * T];
        unsigned r3 = binned[i + 3 * T];
        unsigned r4 = binned[i + 4 * T];
        unsigned r5 = binned[i + 5 * T];
        unsigned r6 = binned[i + 6 * T];
        unsigned r7 = binned[i + 7 * T];
        atomicAdd(&cnt[r0 & (CH - 1)], 1);
        atomicAdd(&cnt[r1 & (CH - 1)], 1);
        atomicAdd(&cnt[r2 & (CH - 1)], 1);
        atomicAdd(&cnt[r3 & (CH - 1)], 1);
        atomicAdd(&cnt[r4 & (CH - 1)], 1);
        atomicAdd(&cnt[r5 & (CH - 1)], 1);
        atomicAdd(&cnt[r6 & (CH - 1)], 1);
        atomicAdd(&cnt[r7 & (CH - 1)], 1);
    }
    for (; i < b; i += T)
        atomicAdd(&cnt[binned[i] & (CH - 1)], 1);
    __syncthreads();
    unsigned short* outp = sliceCnt + ((size_t)(p * NSL + g * NSL2 + s) << SHIFT);
    for (int t = threadIdx.x; t < CH; t += T) outp[t] = (unsigned short)cnt[t];
}

// node pass 1: deg = 1 + sum_s sliceCnt; dinv = rsqrt; pbuf = dinv*x
__global__ void k_node1deg(const float* __restrict__ x, const unsigned short* __restrict__ sliceCnt,
                           float* __restrict__ dinv, float* __restrict__ pbuf, int n) {
    int i = blockIdx.x * blockDim.x + threadIdx.x;
    if (i >= n) return;
    int p = i >> SHIFT, d = i & (CH - 1);
    const unsigned short* base = sliceCnt + (((size_t)p * NSL) << SHIFT) + d;
    int run = 0;
#pragma unroll 8
    for (int s = 0; s < NSL; ++s) run += (int)base[(size_t)s << SHIFT];
    float dv = rsqrtf(1.0f + (float)run);
    dinv[i] = dv;
    pbuf[i] = dv * x[i];
}

// weighted aggregation per (vbin, slice), 8-deep ILP: lds[localdst] += v[src]; flush dense
__global__ void k_aggbin(const unsigned* __restrict__ binned, const int* __restrict__ cursor2,
                         int capg, const float* __restrict__ v, float* __restrict__ part) {
    const int s = blockIdx.x % NSL2;
    const int vb = blockIdx.x / NSL2;
    const int p = vb / NSH, g = vb % NSH;
    __shared__ float lds[CH];
    for (int t = threadIdx.x; t < CH; t += T) lds[t] = 0.f;
    __syncthreads();
    const int s0 = vb * capg;
    const int len = cursor2[g * 32 + p];
    const int a = s0 + (int)((long)s * len / NSL2);
    const int b = s0 + (int)((long)(s + 1) * len / NSL2);
    int i = a + threadIdx.x;
    for (; i + 7 * T < b; i += 8 * T) {
        unsigned r0 = binned[i];
        unsigned r1 = binned[i + T];
        unsigned r2 = binned[i + 2 * T];
        unsigned r3 = binned[i + 3 * T];
        unsigned r4 = binned[i + 4 * T];
        unsigned r5 = binned[i + 5 * T];
        unsigned r6 = binned[i + 6 * T];
        unsigned r7 = binned[i + 7 * T];
        float v0 = v[r0 >> SHIFT];
        float v1 = v[r1 >> SHIFT];
        float v2 = v[r2 >> SHIFT];
        float v3 = v[r3 >> SHIFT];
        float v4 = v[r4 >> SHIFT];
        float v5 = v[r5 >> SHIFT];
        float v6 = v[r6 >> SHIFT];
        float v7 = v[r7 >> SHIFT];
        atomicAdd(&lds[r0 & (CH - 1)], v0);
        atomicAdd(&lds[r1 & (CH - 1)], v1);
        atomicAdd(&lds[r2 & (CH - 1)], v2);
        atomicAdd(&lds[r3 & (CH - 1)], v3);
        atomicAdd(&lds[r4 & (CH - 1)], v4);
        atomicAdd(&lds[r5 & (CH - 1)], v5);
        atomicAdd(&lds[r6 & (CH - 1)], v6);
        atomicAdd(&lds[r7 & (CH - 1)], v7);
    }
    for (; i < b; i += T) {
        unsigned r = binned[i];
        atomicAdd(&lds[r & (CH - 1)], v[r >> SHIFT]);
    }
    __syncthreads();
    float* outp = part + ((size_t)(p * NSL + g * NSL2 + s) << SHIFT);
    for (int t = threadIdx.x; t < CH; t += T) outp[t] = lds[t];
}

// combine 1: t1 = pbuf + sum_s part; MLP; qbuf = dinv*h2
__global__ void k_comb1(const float* __restrict__ dinv, const float* __restrict__ pbuf,
                        const float* __restrict__ part,
                        const float* __restrict__ W1, const float* __restrict__ b1,
                        const float* __restrict__ W2,
                        float* __restrict__ qbuf, int n) {
    int i = blockIdx.x * blockDim.x + threadIdx.x;
    if (i >= n) return;
    int p = i >> SHIFT, d = i & (CH - 1);
    const float* base = part + (((size_t)p * NSL) << SHIFT) + d;
    float acc = 0.f;
#pragma unroll 8
    for (int s = 0; s < NSL; ++s) acc += base[(size_t)s << SHIFT];
    float t1 = pbuf[i] + acc;          // self-loop + neighbors
    float dv = dinv[i];
    float u = dv * t1;
    float h2 = 0.f;
#pragma unroll
    for (int f = 0; f < 16; ++f) {
        float h = fmaxf(fmaf(u, W1[f], b1[f]), 0.f);
        h2 = fmaf(h, W2[f], h2);
    }
    qbuf[i] = dv * h2;
}

// combine 2: t2 = qbuf + sum_s part; out = dinv*t2 + b2
__global__ void k_comb2(const float* __restrict__ dinv, const float* __restrict__ qbuf,
                        const float* __restrict__ part,
                        const float* __restrict__ b2, float* __restrict__ out, int n) {
    int i = blockIdx.x * blockDim.x + threadIdx.x;
    if (i >= n) return;
    int p = i >> SHIFT, d = i & (CH - 1);
    const float* base = part + (((size_t)p * NSL) << SHIFT) + d;
    float acc = 0.f;
#pragma unroll 8
    for (int s = 0; s < NSL; ++s) acc += base[(size_t)s << SHIFT];
    float t2 = qbuf[i] + acc;
    out[i] = fmaf(dinv[i], t2, b2[0]);
}

// ---------- fallback: round-4 global-atomic path ----------

__global__ void k_zero(float* __restrict__ c, int total) {
    int nvec = total >> 2;
    float4* c4 = (float4*)c;
    int i = blockIdx.x * blockDim.x + threadIdx.x;
    int stride = gridDim.x * blockDim.x;
    float4 z = {0.f, 0.f, 0.f, 0.f};
    for (int j = i; j < nvec; j += stride) c4[j] = z;
    if (i < (total & 3)) c[(nvec << 2) + i] = 0.f;
}

__global__ void k_count_atomic(const int* __restrict__ dst, int e,
                               float* __restrict__ copies, int n, int kmask) {
    float* c = copies + (size_t)(blockIdx.x & kmask) * n;
    int i = blockIdx.x * blockDim.x + threadIdx.x;
    int base = i * 4;
    if (base + 4 <= e) {
        int4 d = *reinterpret_cast<const int4*>(dst + base);
        unsafeAtomicAdd(&c[d.x], 1.0f);
        unsafeAtomicAdd(&c[d.y], 1.0f);
        unsafeAtomicAdd(&c[d.z], 1.0f);
        unsafeAtomicAdd(&c[d.w], 1.0f);
    } else {
        for (int j = base; j < e; ++j) unsafeAtomicAdd(&c[dst[j]], 1.0f);
    }
}

__global__ void k_scatter_atomic(const int* __restrict__ src, const int* __restrict__ dst,
                                 const float* __restrict__ v,
                                 float* __restrict__ copies, int n, int kmask, int e) {
    float* c = copies + (size_t)(blockIdx.x & kmask) * n;
    int i = blockIdx.x * blockDim.x + threadIdx.x;
    int base = i * 4;
    if (base + 4 <= e) {
        int4 s = *reinterpret_cast<const int4*>(src + base);
        int4 d = *reinterpret_cast<const int4*>(dst + base);
        float vx = v[s.x], vy = v[s.y], vz = v[s.z], vw = v[s.w];
        unsafeAtomicAdd(&c[d.x], vx);
        unsafeAtomicAdd(&c[d.y], vy);
        unsafeAtomicAdd(&c[d.z], vz);
        unsafeAtomicAdd(&c[d.w], vw);
    } else {
        for (int j = base; j < e; ++j) unsafeAtomicAdd(&c[dst[j]], v[src[j]]);
    }
}

__global__ void k_node1(const float* __restrict__ x, float* __restrict__ copies,
                        float* __restrict__ dinv, float* __restrict__ p,
                        int n, int K, int rz) {
    int i = blockIdx.x * blockDim.x + threadIdx.x;
    if (i < n) {
        float s = 1.0f;
        for (int k = 0; k < K; ++k) {
            s += copies[(size_t)k * n + i];
            if (rz) copies[(size_t)k * n + i] = 0.f;
        }
        float dv = rsqrtf(s);
        dinv[i] = dv;
        p[i] = dv * x[i];
    }
}

__global__ void k_node2(const float* __restrict__ dinv, const float* __restrict__ p,
                        float* __restrict__ copies,
                        const float* __restrict__ W1, const float* __restrict__ b1,
                        const float* __restrict__ W2,
                        float* __restrict__ q, int n, int K, int rz) {
    int i = blockIdx.x * blockDim.x + threadIdx.x;
    if (i < n) {
        float t1 = p[i];
        for (int k = 0; k < K; ++k) {
            t1 += copies[(size_t)k * n + i];
            if (rz) copies[(size_t)k * n + i] = 0.f;
        }
        float dv = dinv[i];
        float u = dv * t1;
        float h2 = 0.0f;
#pragma unroll
        for (int f = 0; f < 16; ++f) {
            float h = fmaxf(fmaf(u, W1[f], b1[f]), 0.0f);
            h2 = fmaf(h, W2[f], h2);
        }
        q[i] = dv * h2;
    }
}

__global__ void k_out(const float* __restrict__ dinv, const float* __restrict__ q,
                      const float* __restrict__ copies,
                      const float* __restrict__ b2, float* __restrict__ out, int n, int K) {
    int i = blockIdx.x * blockDim.x + threadIdx.x;
    if (i < n) {
        float t2 = q[i];
        for (int k = 0; k < K; ++k) t2 += copies[(size_t)k * n + i];
        out[i] = fmaf(dinv[i], t2, b2[0]);
    }
}

// ==============================================================================

extern "C" void kernel_launch(void* const* d_in, const int* in_sizes, int n_in,
                              void* d_out, int out_size, void* d_ws, size_t ws_size,
                              hipStream_t stream) {
    const float* x  = (const float*)d_in[0];
    const float* W1 = (const float*)d_in[1];
    const float* b1 = (const float*)d_in[2];
    const float* W2 = (const float*)d_in[3];
    const float* b2 = (const float*)d_in[4];
    const int*   ei = (const int*)d_in[5];   // [2, E] int32

    const int n = in_sizes[0];        // 100000
    const int e = in_sizes[5] / 2;    // 3200000
    const int* src = ei;
    const int* dst = ei + e;

    float* out = (float*)d_out;
    const int nb_n = (n + T - 1) / T;
    const size_t units = ws_size / 4;
    const int P = (n + CH - 1) / CH;  // 25 for n=100000
    const int capg = e / (P * NSH) + 8192;   // per (partition,shadow) region capacity

    // ---- workspace layout ----
    float* dinv = (float*)d_ws;                       // n
    float* pbuf = dinv + n;                           // n
    float* qbuf = pbuf + n;                           // n
    int* cursor2 = (int*)(qbuf + n);                  // NSH*32
    unsigned* binned = (unsigned*)(cursor2 + NSH * 32);  // P*NSH*capg
    long long capE = (long long)P * NSH * capg;
    unsigned short* sliceCnt = (unsigned short*)(binned + capE);   // P*NSL*CH ushort
    float* part   = (float*)(sliceCnt + (size_t)P * NSL * CH);     // P*NSL*CH

    long long needed = 3LL * n + NSH * 32 + capE
                     + (long long)P * NSL * CH / 2 + (long long)P * NSL * CH;

    if (P <= PMAX && n <= PMAX * CH && (long long)units >= needed) {
        // =========== shadow-region binning + binned partial-chunk path (NSL=32, ILP8) ===========
        const int nbps = P * NSH * NSL2;   // 800
        hipMemsetAsync(cursor2, 0, NSH * 32 * sizeof(int), stream);
        k_binfused<<<BB, T, 0, stream>>>(src, dst, e, P, capg, cursor2, binned);
        k_histA<<<nbps, T, 0, stream>>>(binned, cursor2, capg, sliceCnt);
        k_node1deg<<<nb_n, T, 0, stream>>>(x, sliceCnt, dinv, pbuf, n);
        k_aggbin<<<nbps, T, 0, stream>>>(binned, cursor2, capg, pbuf, part);
        k_comb1<<<nb_n, T, 0, stream>>>(dinv, pbuf, part, W1, b1, W2, qbuf, n);
        k_aggbin<<<nbps, T, 0, stream>>>(binned, cursor2, capg, qbuf, part);
        k_comb2<<<nb_n, T, 0, stream>>>(dinv, qbuf, part, b2, out, n);
        return;
    }

    // ---- fallback (round-4): shadow-copy global atomics ----
    float* p      = dinv + n;
    float* q      = p + n;
    float* copies = q + n;
    long long avail = (long long)units - 3LL * n;
    int K = 1;
    while (K * 2 <= 8 && (long long)(K * 2) * n <= avail) K *= 2;
    const int kmask = K - 1;
    const int e4   = (e + 3) / 4;
    const int nb_e = (e4 + T - 1) / T;
    const int nb_z = min(((K * n / 4) + T - 1) / T, 2048);

    k_zero<<<nb_z, T, 0, stream>>>(copies, K * n);
    k_count_atomic<<<nb_e, T, 0, stream>>>(dst, e, copies, n, kmask);
    k_node1<<<nb_n, T, 0, stream>>>(x, copies, dinv, p, n, K, 1);
    k_scatter_atomic<<<nb_e, T, 0, stream>>>(src, dst, p, copies, n, kmask, e);
    k_node2<<<nb_n, T, 0, stream>>>(dinv, p, copies, W1, b1, W2, q, n, K, 1);
    k_scatter_atomic<<<nb_e, T, 0, stream>>>(src, dst, q, copies, n, kmask, e);
    k_out<<<nb_n, T, 0, stream>>>(dinv, q, copies, b2, out, n, K);
}

// Round 23
// 98.268 us; speedup vs baseline: 1.0297x; 1.0297x over previous
//
#include <hip/hip_runtime.h>

#define T 256
#define CH 4096          // bin width (12-bit localdst), 16 KB LDS
#define SHIFT 12
#define BB 1024          // binning blocks (4/CU)
#define NWV 4            // waves per block
#define NSH 8            // shadow regions per partition (blockIdx & 7)
#define NSL2 4           // slices per virtual bin (r20 optimum)
#define NSL 32           // = NSH*NSL2, slices per partition
#define PMAX 32

// ---------- fused count+reserve+place: closed-form shadow regions ----------
__global__ void k_binfused(const int* __restrict__ src, const int* __restrict__ dst,
                           int e, int P, int capg, int* __restrict__ cursor2,
                           unsigned* __restrict__ binned) {
    const int b = blockIdx.x;
    const int t = threadIdx.x;
    const int lane = t & 63, w = t >> 6;
    __shared__ int wcnt[NWV][PMAX];
    __shared__ int lbase[NWV][PMAX];
    __shared__ int lcur[NWV][PMAX];

    // ---- loop 1: per-thread register counts ----
    int cnt[PMAX];
#pragma unroll
    for (int k = 0; k < PMAX; ++k) cnt[k] = 0;
    const int nv4 = e >> 2;
    const int s4 = (int)((long)b * nv4 / BB);
    const int e4 = (int)((long)(b + 1) * nv4 / BB);
    const int4* d4 = (const int4*)dst;
    const int4* s4p = (const int4*)src;
    for (int i = s4 + t; i < e4; i += T) {
        int4 d = d4[i];
        int px = d.x >> SHIFT, py = d.y >> SHIFT, pz = d.z >> SHIFT, pw = d.w >> SHIFT;
#pragma unroll
        for (int k = 0; k < PMAX; ++k)
            cnt[k] += (px == k) + (py == k) + (pz == k) + (pw == k);
    }
    if (b == BB - 1) {
        for (int j = (nv4 << 2) + t; j < e; j += T) {
            int p = dst[j] >> SHIFT;
#pragma unroll
            for (int k = 0; k < PMAX; ++k) cnt[k] += (p == k);
        }
    }
    // ---- per-wave reduce into LDS ----
#pragma unroll
    for (int k = 0; k < PMAX; ++k) {
        int v = cnt[k];
        for (int off = 32; off; off >>= 1) v += __shfl_down(v, off);
        if (lane == 0) wcnt[w][k] = v;
    }
    __syncthreads();
    // ---- reserve: one atomic per (block, partition) on the block's shadow cursor ----
    if (t < P) {
        int c0 = wcnt[0][t], c1 = wcnt[1][t], c2 = wcnt[2][t], c3 = wcnt[3][t];
        int tot = c0 + c1 + c2 + c3;
        int g = b & (NSH - 1);
        int off = tot ? atomicAdd(&cursor2[g * 32 + t], tot) : 0;
        int base = (t * NSH + g) * capg + off;      // closed-form region start, no division
        lbase[0][t] = base;                lcur[0][t] = 0;
        lbase[1][t] = base + c0;           lcur[1][t] = 0;
        lbase[2][t] = base + c0 + c1;      lcur[2][t] = 0;
        lbase[3][t] = base + c0 + c1 + c2; lcur[3][t] = 0;
    }
    __syncthreads();

    // ---- loop 2: place via per-wave LDS cursors ----
    for (int i = s4 + t; i < e4; i += T) {
        int4 d = d4[i];
        int4 s = s4p[i];
        int pb, off;
        pb = d.x >> SHIFT; off = atomicAdd(&lcur[w][pb], 1);
        binned[lbase[w][pb] + off] = ((unsigned)s.x << SHIFT) | (unsigned)(d.x & (CH - 1));
        pb = d.y >> SHIFT; off = atomicAdd(&lcur[w][pb], 1);
        binned[lbase[w][pb] + off] = ((unsigned)s.y << SHIFT) | (unsigned)(d.y & (CH - 1));
        pb = d.z >> SHIFT; off = atomicAdd(&lcur[w][pb], 1);
        binned[lbase[w][pb] + off] = ((unsigned)s.z << SHIFT) | (unsigned)(d.z & (CH - 1));
        pb = d.w >> SHIFT; off = atomicAdd(&lcur[w][pb], 1);
        binned[lbase[w][pb] + off] = ((unsigned)s.w << SHIFT) | (unsigned)(d.w & (CH - 1));
    }
    if (b == BB - 1) {
        for (int j = (nv4 << 2) + t; j < e; j += T) {
            int d = dst[j];
            int pb = d >> SHIFT;
            int off = atomicAdd(&lcur[w][pb], 1);
            binned[lbase[w][pb] + off] = ((unsigned)src[j] << SHIFT) | (unsigned)(d & (CH - 1));
        }
    }
}

// ---------- degree histogram per (vbin, slice), 4-deep ILP, ushort output ----------
__global__ void k_histA(const unsigned* __restrict__ binned, const int* __restrict__ cursor2,
                        int capg, unsigned short* __restrict__ sliceCnt) {
    const int s = blockIdx.x % NSL2;
    const int vb = blockIdx.x / NSL2;          // vb = p*NSH + g
    const int p = vb / NSH, g = vb % NSH;
    __shared__ int cnt[CH];
    for (int t = threadIdx.x; t < CH; t += T) cnt[t] = 0;
    __syncthreads();
    const int s0 = vb * capg;
    const int len = cursor2[g * 32 + p];
    const int a = s0 + (int)((long)s * len / NSL2);
    const int b = s0 + (int)((long)(s + 1) * len / NSL2);
    int i = a + threadIdx.x;
    for (; i + 3 * T < b; i += 4 * T) {
        unsigned r0 = binned[i];
        unsigned r1 = binned[i + T];
        unsigned r2 = binned[i + 2 * T];
        unsigned r3 = binned[i + 3 * T];
        atomicAdd(&cnt[r0 & (CH - 1)], 1);
        atomicAdd(&cnt[r1 & (CH - 1)], 1);
        atomicAdd(&cnt[r2 & (CH - 1)], 1);
        atomicAdd(&cnt[r3 & (CH - 1)], 1);
    }
    for (; i < b; i += T)
        atomicAdd(&cnt[binned[i] & (CH - 1)], 1);
    __syncthreads();
    unsigned short* outp = sliceCnt + ((size_t)(p * NSL + g * NSL2 + s) << SHIFT);
    for (int t = threadIdx.x; t < CH; t += T) outp[t] = (unsigned short)cnt[t];
}

// node pass 1: deg = 1 + sum_s sliceCnt; dinv = rsqrt; pbuf = dinv*x
__global__ void k_node1deg(const float* __restrict__ x, const unsigned short* __restrict__ sliceCnt,
                           float* __restrict__ dinv, float* __restrict__ pbuf, int n) {
    int i = blockIdx.x * blockDim.x + threadIdx.x;
    if (i >= n) return;
    int p = i >> SHIFT, d = i & (CH - 1);
    const unsigned short* base = sliceCnt + (((size_t)p * NSL) << SHIFT) + d;
    int run = 0;
#pragma unroll 8
    for (int s = 0; s < NSL; ++s) run += (int)base[(size_t)s << SHIFT];
    float dv = rsqrtf(1.0f + (float)run);
    dinv[i] = dv;
    pbuf[i] = dv * x[i];
}

// weighted aggregation per (vbin, slice), 4-deep ILP: lds[localdst] += v[src]; flush dense
__global__ void k_aggbin(const unsigned* __restrict__ binned, const int* __restrict__ cursor2,
                         int capg, const float* __restrict__ v, float* __restrict__ part) {
    const int s = blockIdx.x % NSL2;
    const int vb = blockIdx.x / NSL2;
    const int p = vb / NSH, g = vb % NSH;
    __shared__ float lds[CH];
    for (int t = threadIdx.x; t < CH; t += T) lds[t] = 0.f;
    __syncthreads();
    const int s0 = vb * capg;
    const int len = cursor2[g * 32 + p];
    const int a = s0 + (int)((long)s * len / NSL2);
    const int b = s0 + (int)((long)(s + 1) * len / NSL2);
    int i = a + threadIdx.x;
    for (; i + 3 * T < b; i += 4 * T) {
        unsigned r0 = binned[i];
        unsigned r1 = binned[i + T];
        unsigned r2 = binned[i + 2 * T];
        unsigned r3 = binned[i + 3 * T];
        float v0 = v[r0 >> SHIFT];
        float v1 = v[r1 >> SHIFT];
        float v2 = v[r2 >> SHIFT];
        float v3 = v[r3 >> SHIFT];
        atomicAdd(&lds[r0 & (CH - 1)], v0);
        atomicAdd(&lds[r1 & (CH - 1)], v1);
        atomicAdd(&lds[r2 & (CH - 1)], v2);
        atomicAdd(&lds[r3 & (CH - 1)], v3);
    }
    for (; i < b; i += T) {
        unsigned r = binned[i];
        atomicAdd(&lds[r & (CH - 1)], v[r >> SHIFT]);
    }
    __syncthreads();
    float* outp = part + ((size_t)(p * NSL + g * NSL2 + s) << SHIFT);
    for (int t = threadIdx.x; t < CH; t += T) outp[t] = lds[t];
}

// combine 1: t1 = pbuf + sum_s part; MLP; qbuf = dinv*h2
__global__ void k_comb1(const float* __restrict__ dinv, const float* __restrict__ pbuf,
                        const float* __restrict__ part,
                        const float* __restrict__ W1, const float* __restrict__ b1,
                        const float* __restrict__ W2,
                        float* __restrict__ qbuf, int n) {
    int i = blockIdx.x * blockDim.x + threadIdx.x;
    if (i >= n) return;
    int p = i >> SHIFT, d = i & (CH - 1);
    const float* base = part + (((size_t)p * NSL) << SHIFT) + d;
    float acc = 0.f;
#pragma unroll 8
    for (int s = 0; s < NSL; ++s) acc += base[(size_t)s << SHIFT];
    float t1 = pbuf[i] + acc;          // self-loop + neighbors
    float dv = dinv[i];
    float u = dv * t1;
    float h2 = 0.f;
#pragma unroll
    for (int f = 0; f < 16; ++f) {
        float h = fmaxf(fmaf(u, W1[f], b1[f]), 0.f);
        h2 = fmaf(h, W2[f], h2);
    }
    qbuf[i] = dv * h2;
}

// combine 2: t2 = qbuf + sum_s part; out = dinv*t2 + b2
__global__ void k_comb2(const float* __restrict__ dinv, const float* __restrict__ qbuf,
                        const float* __restrict__ part,
                        const float* __restrict__ b2, float* __restrict__ out, int n) {
    int i = blockIdx.x * blockDim.x + threadIdx.x;
    if (i >= n) return;
    int p = i >> SHIFT, d = i & (CH - 1);
    const float* base = part + (((size_t)p * NSL) << SHIFT) + d;
    float acc = 0.f;
#pragma unroll 8
    for (int s = 0; s < NSL; ++s) acc += base[(size_t)s << SHIFT];
    float t2 = qbuf[i] + acc;
    out[i] = fmaf(dinv[i], t2, b2[0]);
}

// ---------- fallback: round-4 global-atomic path ----------

__global__ void k_zero(float* __restrict__ c, int total) {
    int nvec = total >> 2;
    float4* c4 = (float4*)c;
    int i = blockIdx.x * blockDim.x + threadIdx.x;
    int stride = gridDim.x * blockDim.x;
    float4 z = {0.f, 0.f, 0.f, 0.f};
    for (int j = i; j < nvec; j += stride) c4[j] = z;
    if (i < (total & 3)) c[(nvec << 2) + i] = 0.f;
}

__global__ void k_count_atomic(const int* __restrict__ dst, int e,
                               float* __restrict__ copies, int n, int kmask) {
    float* c = copies + (size_t)(blockIdx.x & kmask) * n;
    int i = blockIdx.x * blockDim.x + threadIdx.x;
    int base = i * 4;
    if (base + 4 <= e) {
        int4 d = *reinterpret_cast<const int4*>(dst + base);
        unsafeAtomicAdd(&c[d.x], 1.0f);
        unsafeAtomicAdd(&c[d.y], 1.0f);
        unsafeAtomicAdd(&c[d.z], 1.0f);
        unsafeAtomicAdd(&c[d.w], 1.0f);
    } else {
        for (int j = base; j < e; ++j) unsafeAtomicAdd(&c[dst[j]], 1.0f);
    }
}

__global__ void k_scatter_atomic(const int* __restrict__ src, const int* __restrict__ dst,
                                 const float* __restrict__ v,
                                 float* __restrict__ copies, int n, int kmask, int e) {
    float* c = copies + (size_t)(blockIdx.x & kmask) * n;
    int i = blockIdx.x * blockDim.x + threadIdx.x;
    int base = i * 4;
    if (base + 4 <= e) {
        int4 s = *reinterpret_cast<const int4*>(src + base);
        int4 d = *reinterpret_cast<const int4*>(dst + base);
        float vx = v[s.x], vy = v[s.y], vz = v[s.z], vw = v[s.w];
        unsafeAtomicAdd(&c[d.x], vx);
        unsafeAtomicAdd(&c[d.y], vy);
        unsafeAtomicAdd(&c[d.z], vz);
        unsafeAtomicAdd(&c[d.w], vw);
    } else {
        for (int j = base; j < e; ++j) unsafeAtomicAdd(&c[dst[j]], v[src[j]]);
    }
}

__global__ void k_node1(const float* __restrict__ x, float* __restrict__ copies,
                        float* __restrict__ dinv, float* __restrict__ p,
                        int n, int K, int rz) {
    int i = blockIdx.x * blockDim.x + threadIdx.x;
    if (i < n) {
        float s = 1.0f;
        for (int k = 0; k < K; ++k) {
            s += copies[(size_t)k * n + i];
            if (rz) copies[(size_t)k * n + i] = 0.f;
        }
        float dv = rsqrtf(s);
        dinv[i] = dv;
        p[i] = dv * x[i];
    }
}

__global__ void k_node2(const float* __restrict__ dinv, const float* __restrict__ p,
                        float* __restrict__ copies,
                        const float* __restrict__ W1, const float* __restrict__ b1,
                        const float* __restrict__ W2,
                        float* __restrict__ q, int n, int K, int rz) {
    int i = blockIdx.x * blockDim.x + threadIdx.x;
    if (i < n) {
        float t1 = p[i];
        for (int k = 0; k < K; ++k) {
            t1 += copies[(size_t)k * n + i];
            if (rz) copies[(size_t)k * n + i] = 0.f;
        }
        float dv = dinv[i];
        float u = dv * t1;
        float h2 = 0.0f;
#pragma unroll
        for (int f = 0; f < 16; ++f) {
            float h = fmaxf(fmaf(u, W1[f], b1[f]), 0.0f);
            h2 = fmaf(h, W2[f], h2);
        }
        q[i] = dv * h2;
    }
}

__global__ void k_out(const float* __restrict__ dinv, const float* __restrict__ q,
                      const float* __restrict__ copies,
                      const float* __restrict__ b2, float* __restrict__ out, int n, int K) {
    int i = blockIdx.x * blockDim.x + threadIdx.x;
    if (i < n) {
        float t2 = q[i];
        for (int k = 0; k < K; ++k) t2 += copies[(size_t)k * n + i];
        out[i] = fmaf(dinv[i], t2, b2[0]);
    }
}

// ==============================================================================

extern "C" void kernel_launch(void* const* d_in, const int* in_sizes, int n_in,
                              void* d_out, int out_size, void* d_ws, size_t ws_size,
                              hipStream_t stream) {
    const float* x  = (const float*)d_in[0];
    const float* W1 = (const float*)d_in[1];
    const float* b1 = (const float*)d_in[2];
    const float* W2 = (const float*)d_in[3];
    const float* b2 = (const float*)d_in[4];
    const int*   ei = (const int*)d_in[5];   // [2, E] int32

    const int n = in_sizes[0];        // 100000
    const int e = in_sizes[5] / 2;    // 3200000
    const int* src = ei;
    const int* dst = ei + e;

    float* out = (float*)d_out;
    const int nb_n = (n + T - 1) / T;
    const size_t units = ws_size / 4;
    const int P = (n + CH - 1) / CH;  // 25 for n=100000
    const int capg = e / (P * NSH) + 8192;   // per (partition,shadow) region capacity

    // ---- workspace layout ----
    float* dinv = (float*)d_ws;                       // n
    float* pbuf = dinv + n;                           // n
    float* qbuf = pbuf + n;                           // n
    int* cursor2 = (int*)(qbuf + n);                  // NSH*32
    unsigned* binned = (unsigned*)(cursor2 + NSH * 32);  // P*NSH*capg
    long long capE = (long long)P * NSH * capg;
    unsigned short* sliceCnt = (unsigned short*)(binned + capE);   // P*NSL*CH ushort
    float* part   = (float*)(sliceCnt + (size_t)P * NSL * CH);     // P*NSL*CH

    long long needed = 3LL * n + NSH * 32 + capE
                     + (long long)P * NSL * CH / 2 + (long long)P * NSL * CH;

    if (P <= PMAX && n <= PMAX * CH && (long long)units >= needed) {
        // =========== shadow-region binning + binned partial-chunk path (r20 optimum) ===========
        const int nbps = P * NSH * NSL2;   // 800
        hipMemsetAsync(cursor2, 0, NSH * 32 * sizeof(int), stream);
        k_binfused<<<BB, T, 0, stream>>>(src, dst, e, P, capg, cursor2, binned);
        k_histA<<<nbps, T, 0, stream>>>(binned, cursor2, capg, sliceCnt);
        k_node1deg<<<nb_n, T, 0, stream>>>(x, sliceCnt, dinv, pbuf, n);
        k_aggbin<<<nbps, T, 0, stream>>>(binned, cursor2, capg, pbuf, part);
        k_comb1<<<nb_n, T, 0, stream>>>(dinv, pbuf, part, W1, b1, W2, qbuf, n);
        k_aggbin<<<nbps, T, 0, stream>>>(binned, cursor2, capg, qbuf, part);
        k_comb2<<<nb_n, T, 0, stream>>>(dinv, qbuf, part, b2, out, n);
        return;
    }

    // ---- fallback (round-4): shadow-copy global atomics ----
    float* p      = dinv + n;
    float* q      = p + n;
    float* copies = q + n;
    long long avail = (long long)units - 3LL * n;
    int K = 1;
    while (K * 2 <= 8 && (long long)(K * 2) * n <= avail) K *= 2;
    const int kmask = K - 1;
    const int e4   = (e + 3) / 4;
    const int nb_e = (e4 + T - 1) / T;
    const int nb_z = min(((K * n / 4) + T - 1) / T, 2048);

    k_zero<<<nb_z, T, 0, stream>>>(copies, K * n);
    k_count_atomic<<<nb_e, T, 0, stream>>>(dst, e, copies, n, kmask);
    k_node1<<<nb_n, T, 0, stream>>>(x, copies, dinv, p, n, K, 1);
    k_scatter_atomic<<<nb_e, T, 0, stream>>>(src, dst, p, copies, n, kmask, e);
    k_node2<<<nb_n, T, 0, stream>>>(dinv, p, copies, W1, b1, W2, q, n, K, 1);
    k_scatter_atomic<<<nb_e, T, 0, stream>>>(src, dst, q, copies, n, kmask, e);
    k_out<<<nb_n, T, 0, stream>>>(dinv, q, copies, b2, out, n, K);
}